// Round 4
// baseline (179.006 us; speedup 1.0000x reference)
//
#include <hip/hip_runtime.h>
#include <hip/hip_bf16.h>

// ClusterLoss fused kernel for MI355X (gfx950).  R4: fp8 whole-B-in-LDS.
// argmax_k feat_n . chat_k with chat in fp8 e4m3 (all 1024 centers resident
// in 144 KB LDS, staged once per block); A loaded global->VGPR as fp8 frags
// (no A LDS). Barrier-free MFMA loop. loss_n = 1 - 2 d na/nf + na^2.
// R3->R4: cvt_pk_fp8_f32 word-select must be an immediate -> template<bool HI>.

#define D 128
#define BSTR 144        // LDS bytes per center row (128 fp8 + 16 pad): 36 dwords -> 2-way banks (free)
#define NK 1024

typedef __attribute__((ext_vector_type(4))) float floatx4;

template <bool HI>
__device__ __forceinline__ unsigned int pk_fp8(float a, float b, unsigned int old) {
    return (unsigned int)__builtin_amdgcn_cvt_pk_fp8_f32(a, b, (int)old, HI);
}

// ---- Prep: normalize centers -> fp8 chat, store fp32 norms; zero d_out ----
__global__ void prep_centers(const float* __restrict__ centers,
                             unsigned char* __restrict__ chat,
                             float* __restrict__ cnorm,
                             float* __restrict__ out) {
    const int k = blockIdx.x;
    const int t = threadIdx.x;            // 128 threads, one per dim
    float v = centers[(size_t)k * D + t];
    float s = v * v;
    #pragma unroll
    for (int m = 1; m <= 32; m <<= 1) s += __shfl_xor(s, m);
    __shared__ float ws2[2];
    if ((t & 63) == 0) ws2[t >> 6] = s;
    __syncthreads();
    float total = ws2[0] + ws2[1];
    float n = sqrtf(total);
    float neff = fmaxf(n, 1e-12f);
    float q = v / neff;
    chat[(size_t)k * D + t] = (unsigned char)(pk_fp8<false>(q, q, 0u) & 0xFFu);
    if (t == 0) cnorm[k] = n;
    if (k == 0 && t == 0) out[0] = 0.0f;
}

// ---- Main: A-direct fp8 frags x whole-B LDS, fused argmax + loss ----
__global__ __launch_bounds__(512, 1) void cluster_main(
    const float* __restrict__ feats,        // [N][128] fp32
    const unsigned char* __restrict__ chat, // [1024][128] fp8 e4m3
    const float* __restrict__ cnorm,        // [1024] fp32
    float* __restrict__ out, int N, int rtPer) {

    extern __shared__ unsigned char Bs[];   // NK * BSTR = 147456 B
    __shared__ float nf_s[128];             // row sum-of-squares
    __shared__ float bv[4][128];            // per-(wn,row) best value
    __shared__ int   bk[4][128];            // per-(wn,row) best index

    const int tid  = threadIdx.x;           // 0..511, 8 waves
    const int lane = tid & 63;
    const int wave = tid >> 6;
    const int wm   = wave & 1;              // row half (64 rows)
    const int wn   = wave >> 1;             // col quarter (256 centers)
    const int m16  = lane & 15;
    const int quad = lane >> 4;

    // ---- Stage ALL of B once: 128 KB, b128 chunks ----
    #pragma unroll
    for (int s = 0; s < 16; ++s) {
        int id = s * 512 + tid;             // 16B chunk id, 0..8191
        int r  = id >> 3;                   // center row
        int c  = id & 7;                    // chunk in row
        uint4 v = *(const uint4*)(chat + r * D + c * 16);
        *(uint4*)&Bs[r * BSTR + c * 16] = v;
    }
    __syncthreads();

    for (int rt = 0; rt < rtPer; ++rt) {
        const int row0 = (blockIdx.x * rtPer + rt) * 128;

        // ---- A: global fp32 -> fp8 frags in regs; fused row sumsq ----
        long long afr[4][4];                // [i][kk], 8 fp8 each
        #pragma unroll
        for (int i = 0; i < 4; ++i) {
            const int r = wm * 64 + i * 16 + m16;
            const float* ap = feats + (size_t)(row0 + r) * D + quad * 8;
            float sq = 0.0f;
            #pragma unroll
            for (int kk = 0; kk < 4; ++kk) {
                float4 v0 = *(const float4*)(ap + kk * 32);
                float4 v1 = *(const float4*)(ap + kk * 32 + 4);
                sq += v0.x*v0.x + v0.y*v0.y + v0.z*v0.z + v0.w*v0.w
                    + v1.x*v1.x + v1.y*v1.y + v1.z*v1.z + v1.w*v1.w;
                unsigned int w0 = pk_fp8<false>(v0.x, v0.y, 0u);
                w0 = pk_fp8<true>(v0.z, v0.w, w0);
                unsigned int w1 = pk_fp8<false>(v1.x, v1.y, 0u);
                w1 = pk_fp8<true>(v1.z, v1.w, w1);
                afr[i][kk] = (long long)(((unsigned long long)w1 << 32) | w0);
            }
            // reduce over quad (lane bits 4,5) -> full row sumsq
            sq += __shfl_xor(sq, 16);
            sq += __shfl_xor(sq, 32);
            if (wn == 0 && quad == 0) nf_s[r] = sq;
        }

        float best[16];
        int   bestk[16];
        #pragma unroll
        for (int s = 0; s < 16; ++s) { best[s] = -1e30f; bestk[s] = 0; }

        // ---- barrier-free MFMA loop over this wave's 256 centers ----
        #pragma unroll
        for (int sub = 0; sub < 4; ++sub) {
            const int cbase = wn * 256 + sub * 64;
            floatx4 acc[4][4];
            #pragma unroll
            for (int i = 0; i < 4; ++i)
                #pragma unroll
                for (int j = 0; j < 4; ++j)
                    acc[i][j] = (floatx4){0.f, 0.f, 0.f, 0.f};

            #pragma unroll
            for (int kk = 0; kk < 4; ++kk) {
                long long bfr[4];
                #pragma unroll
                for (int j = 0; j < 4; ++j)
                    bfr[j] = *(const long long*)&Bs[(cbase + j * 16 + m16) * BSTR + kk * 32 + quad * 8];
                #pragma unroll
                for (int i = 0; i < 4; ++i)
                    #pragma unroll
                    for (int j = 0; j < 4; ++j)
                        acc[i][j] = __builtin_amdgcn_mfma_f32_16x16x32_fp8_fp8(
                            afr[i][kk], bfr[j], acc[i][j], 0, 0, 0);
            }

            // per-lane argmax; ascending k + strict > == ties-to-smaller-k
            #pragma unroll
            for (int i = 0; i < 4; ++i)
                #pragma unroll
                for (int r = 0; r < 4; ++r) {
                    const int slot = i * 4 + r;
                    #pragma unroll
                    for (int j = 0; j < 4; ++j) {
                        float v = acc[i][j][r];
                        int   k = cbase + j * 16 + m16;
                        if (v > best[slot]) { best[slot] = v; bestk[slot] = k; }
                    }
                }
        }

        // cross-m16 butterfly (same rows, different cols)
        #pragma unroll
        for (int mask = 1; mask <= 8; mask <<= 1)
            #pragma unroll
            for (int s = 0; s < 16; ++s) {
                float ov = __shfl_xor(best[s], mask);
                int   ok = __shfl_xor(bestk[s], mask);
                if (ov > best[s] || (ov == best[s] && ok < bestk[s])) {
                    best[s] = ov; bestk[s] = ok;
                }
            }

        if (m16 == 0) {
            #pragma unroll
            for (int s = 0; s < 16; ++s) {
                int i = s >> 2, rr = s & 3;
                int row = wm * 64 + 16 * i + quad * 4 + rr;
                bv[wn][row] = best[s];
                bk[wn][row] = bestk[s];
            }
        }
        __syncthreads();

        // combine 4 col-quarters; loss; block reduce
        if (tid < 128) {
            const int row = tid;
            float d = bv[0][row]; int ka = bk[0][row];
            #pragma unroll
            for (int w = 1; w < 4; ++w) {
                float v = bv[w][row]; int k = bk[w][row];
                if (v > d || (v == d && k < ka)) { d = v; ka = k; }
            }
            float nf = fmaxf(sqrtf(nf_s[row]), 1e-12f);
            float na = cnorm[ka];
            float lsum = 1.0f - 2.0f * d * na / nf + na * na;
            #pragma unroll
            for (int m = 1; m <= 32; m <<= 1) lsum += __shfl_xor(lsum, m);
            if (lane == 0) atomicAdd(out, lsum / (float)N);
        }
        __syncthreads();   // protect nf_s/bv/bk for next row-tile
    }
}

extern "C" void kernel_launch(void* const* d_in, const int* in_sizes, int n_in,
                              void* d_out, int out_size, void* d_ws, size_t ws_size,
                              hipStream_t stream) {
    const float* feats   = (const float*)d_in[0];
    const float* centers = (const float*)d_in[1];
    const int N = in_sizes[0] / D;   // 131072
    const int K = in_sizes[1] / D;   // 1024

    unsigned char* chat = (unsigned char*)d_ws;                    // 1024*128 fp8 = 128 KB
    float* cnorm = (float*)((char*)d_ws + (size_t)K * D);          // K fp32
    float* out = (float*)d_out;

    const int smem = NK * BSTR;  // 147456 B
    (void)hipFuncSetAttribute((const void*)cluster_main,
                              hipFuncAttributeMaxDynamicSharedMemorySize, smem);

    prep_centers<<<K, D, 0, stream>>>(centers, chat, cnorm, out);

    const int nTiles = N / 128;              // 1024
    const int grid = 256;
    const int rtPer = nTiles / grid;         // 4
    cluster_main<<<grid, 512, smem, stream>>>(feats, chat, cnorm, out, N, rtPer);
}

// Round 5
// 176.643 us; speedup vs baseline: 1.0134x; 1.0134x over previous
//
#include <hip/hip_runtime.h>
#include <hip/hip_bf16.h>

// ClusterLoss fused kernel for MI355X (gfx950).  R5.
// Whole-B-in-LDS fp8 (XOR-swizzled, unpadded, 128 KB) + coalesced A staging
// through a 16 KB swizzled LDS tile; 1024 threads (16 waves, 4/SIMD).
// argmax_k feat_n . chat_k ; loss_n = 1 - 2 d na/nf + na^2 (fp32 scalars).

#define D 128
#define NK 1024

typedef __attribute__((ext_vector_type(4))) float floatx4;

template <bool HI>
__device__ __forceinline__ unsigned int pk_fp8(float a, float b, unsigned int old) {
    return (unsigned int)__builtin_amdgcn_cvt_pk_fp8_f32(a, b, (int)old, HI);
}

// ---- Prep: normalize centers -> fp8 chat, store fp32 norms; zero d_out ----
__global__ void prep_centers(const float* __restrict__ centers,
                             unsigned char* __restrict__ chat,
                             float* __restrict__ cnorm,
                             float* __restrict__ out) {
    const int k = blockIdx.x;
    const int t = threadIdx.x;            // 128 threads, one per dim
    float v = centers[(size_t)k * D + t];
    float s = v * v;
    #pragma unroll
    for (int m = 1; m <= 32; m <<= 1) s += __shfl_xor(s, m);
    __shared__ float ws2[2];
    if ((t & 63) == 0) ws2[t >> 6] = s;
    __syncthreads();
    float total = ws2[0] + ws2[1];
    float n = sqrtf(total);
    float neff = fmaxf(n, 1e-12f);
    float q = v / neff;
    chat[(size_t)k * D + t] = (unsigned char)(pk_fp8<false>(q, q, 0u) & 0xFFu);
    if (t == 0) cnorm[k] = n;
    if (k == 0 && t == 0) out[0] = 0.0f;
}

// ---- Main ----
__global__ __launch_bounds__(1024, 1) void cluster_main(
    const float* __restrict__ feats,        // [N][128] fp32
    const unsigned char* __restrict__ chat, // [1024][128] fp8 e4m3
    const float* __restrict__ cnorm,        // [1024] fp32
    float* __restrict__ out, int N, int rtPer) {

    extern __shared__ unsigned char lds[];
    unsigned char* Bs = lds;                 // 131072 B, swizzled
    unsigned char* As = lds + NK * D;        // 16384 B, swizzled
    __shared__ float nf_s[128];
    __shared__ float bv[8][128];
    __shared__ int   bk[8][128];

    const int tid  = threadIdx.x;            // 0..1023, 16 waves
    const int lane = tid & 63;
    const int wave = tid >> 6;
    const int wm   = wave & 1;               // row half (64 rows)
    const int wn   = wave >> 1;              // col slice (128 centers)
    const int m16  = lane & 15;
    const int quad = lane >> 4;              // 0..3
    const int q1   = quad >> 1, q0 = quad & 1;
    const int m8   = m16 & 7;

    // ---- Stage ALL of B once: 8192 16B chunks, 8/thread, swizzled ----
    #pragma unroll
    for (int s = 0; s < 8; ++s) {
        int id = s * 1024 + tid;
        int r  = id >> 3;                    // center row
        int c  = id & 7;                     // logical 16B chunk
        uint4 v = *(const uint4*)(chat + (size_t)r * D + c * 16);
        *(uint4*)&Bs[r * D + ((c ^ (r & 7)) << 4)] = v;
    }

    for (int rt = 0; rt < rtPer; ++rt) {
        const int row0 = (blockIdx.x * rtPer + rt) * 128;

        // ---- Stage A (coalesced float4 -> fp8, swizzled) + row sumsq ----
        #pragma unroll
        for (int s = 0; s < 4; ++s) {
            int id = s * 1024 + tid;         // float4 chunk, 0..4095
            int r  = id >> 5;                // row (32 chunks/row)
            int c4 = id & 31;
            float4 v = *(const float4*)(feats + (size_t)(row0 + r) * D + c4 * 4);
            unsigned int w = pk_fp8<false>(v.x, v.y, 0u);
            w = pk_fp8<true>(v.z, v.w, w);
            int pc = (c4 >> 2) ^ (r & 7);    // swizzled 16B chunk
            *(unsigned int*)&As[r * D + pc * 16 + (c4 & 3) * 4] = w;
            float sq = v.x*v.x + v.y*v.y + v.z*v.z + v.w*v.w;
            #pragma unroll
            for (int m = 1; m <= 16; m <<= 1) sq += __shfl_xor(sq, m);
            if ((tid & 31) == 0) nf_s[r] = sq;
        }
        __syncthreads();                     // B (rt 0) + A + nf_s visible

        // ---- A fragments from LDS (2-way banks, free) ----
        long long afr[4][4];                 // [i][kk]
        #pragma unroll
        for (int i = 0; i < 4; ++i) {
            const int r = wm * 64 + i * 16 + m16;
            #pragma unroll
            for (int kk = 0; kk < 4; ++kk) {
                int pc = (2 * kk + q1) ^ m8;
                afr[i][kk] = *(const long long*)&As[r * D + pc * 16 + q0 * 8];
            }
        }

        float best[16];
        int   bestk[16];
        #pragma unroll
        for (int s = 0; s < 16; ++s) { best[s] = -1e30f; bestk[s] = 0; }

        // ---- barrier-free MFMA over this wave's 128-center slice ----
        #pragma unroll
        for (int ch = 0; ch < 4; ++ch) {     // 4 chunks of 32 centers
            const int cbase = wn * 128 + ch * 32;
            floatx4 acc[4][2];
            #pragma unroll
            for (int i = 0; i < 4; ++i)
                #pragma unroll
                for (int j = 0; j < 2; ++j)
                    acc[i][j] = (floatx4){0.f, 0.f, 0.f, 0.f};

            #pragma unroll
            for (int kk = 0; kk < 4; ++kk) {
                long long bfr[2];
                #pragma unroll
                for (int j = 0; j < 2; ++j) {
                    int k  = cbase + j * 16 + m16;
                    int pc = (2 * kk + q1) ^ m8;
                    bfr[j] = *(const long long*)&Bs[k * D + pc * 16 + q0 * 8];
                }
                #pragma unroll
                for (int i = 0; i < 4; ++i)
                    #pragma unroll
                    for (int j = 0; j < 2; ++j)
                        acc[i][j] = __builtin_amdgcn_mfma_f32_16x16x32_fp8_fp8(
                            afr[i][kk], bfr[j], acc[i][j], 0, 0, 0);
            }

            // per-lane argmax; ascending k + strict > == ties-to-smaller-k
            #pragma unroll
            for (int i = 0; i < 4; ++i)
                #pragma unroll
                for (int r = 0; r < 4; ++r) {
                    const int slot = i * 4 + r;
                    #pragma unroll
                    for (int j = 0; j < 2; ++j) {
                        float v = acc[i][j][r];
                        int   k = cbase + j * 16 + m16;
                        if (v > best[slot]) { best[slot] = v; bestk[slot] = k; }
                    }
                }
        }

        // cross-m16 butterfly (same rows, different cols)
        #pragma unroll
        for (int mask = 1; mask <= 8; mask <<= 1)
            #pragma unroll
            for (int s = 0; s < 16; ++s) {
                float ov = __shfl_xor(best[s], mask);
                int   ok = __shfl_xor(bestk[s], mask);
                if (ov > best[s] || (ov == best[s] && ok < bestk[s])) {
                    best[s] = ov; bestk[s] = ok;
                }
            }

        if (m16 == 0) {
            #pragma unroll
            for (int s = 0; s < 16; ++s) {
                int i = s >> 2, rr = s & 3;
                int row = wm * 64 + 16 * i + quad * 4 + rr;
                bv[wn][row] = best[s];
                bk[wn][row] = bestk[s];
            }
        }
        __syncthreads();

        // ---- combine 8 col-slices; loss; reduce ----
        if (tid < 128) {
            const int row = tid;
            float d = bv[0][row]; int ka = bk[0][row];
            #pragma unroll
            for (int w = 1; w < 8; ++w) {    // ascending k ranges
                float v = bv[w][row]; int k = bk[w][row];
                if (v > d || (v == d && k < ka)) { d = v; ka = k; }
            }
            float nf = fmaxf(sqrtf(nf_s[row]), 1e-12f);
            float na = cnorm[ka];
            float lsum = 1.0f - 2.0f * d * na / nf + na * na;
            #pragma unroll
            for (int m = 1; m <= 32; m <<= 1) lsum += __shfl_xor(lsum, m);
            if (lane == 0) atomicAdd(out, lsum / (float)N);
        }
        __syncthreads();   // protect As/nf_s/bv/bk before next rt
    }
}

extern "C" void kernel_launch(void* const* d_in, const int* in_sizes, int n_in,
                              void* d_out, int out_size, void* d_ws, size_t ws_size,
                              hipStream_t stream) {
    const float* feats   = (const float*)d_in[0];
    const float* centers = (const float*)d_in[1];
    const int N = in_sizes[0] / D;   // 131072
    const int K = in_sizes[1] / D;   // 1024

    unsigned char* chat = (unsigned char*)d_ws;                    // 1024*128 fp8 = 128 KB
    float* cnorm = (float*)((char*)d_ws + (size_t)K * D);          // K fp32
    float* out = (float*)d_out;

    const int smem = NK * D + 128 * D;   // 147456 B dynamic
    (void)hipFuncSetAttribute((const void*)cluster_main,
                              hipFuncAttributeMaxDynamicSharedMemorySize, smem);

    prep_centers<<<K, D, 0, stream>>>(centers, chat, cnorm, out);

    const int nTiles = N / 128;              // 1024
    const int grid = 256;
    const int rtPer = nTiles / grid;         // 4
    cluster_main<<<grid, 1024, smem, stream>>>(feats, chat, cnorm, out, N, rtPer);
}

// Round 6
// 154.996 us; speedup vs baseline: 1.1549x; 1.1397x over previous
//
#include <hip/hip_runtime.h>
#include <hip/hip_bf16.h>

// ClusterLoss fused kernel for MI355X (gfx950).  R6.
// Whole-B-in-LDS fp8 (XOR-swizzled, 128 KB) + coalesced A staging via 16 KB
// swizzled LDS; 1024 threads (16 waves, 4/SIMD), launch_bounds(1024,4) to fix
// the R5 spill regression (VGPR=64 + 14 MB scratch traffic).
// Argmax via keyed floats: low 10 mantissa bits of each dot replaced by
// (1023-k) (v_bfi), reduced with pure v_max_f32/max3 -> no cmp/cndmask
// chains, no bestk registers. Ties -> smaller k. Decode at epilogue.
// loss_n = 1 - 2 d na/nf + na^2 (fp32 scalars).

#define D 128
#define NK 1024

typedef __attribute__((ext_vector_type(4))) float floatx4;

template <bool HI>
__device__ __forceinline__ unsigned int pk_fp8(float a, float b, unsigned int old) {
    return (unsigned int)__builtin_amdgcn_cvt_pk_fp8_f32(a, b, (int)old, HI);
}

__device__ __forceinline__ float key_pack(float v, unsigned int inv_k) {
    unsigned int u = __builtin_bit_cast(unsigned int, v);
    // (mask & inv_k) | (~mask & u)  ->  v_bfi_b32
    unsigned int r = (0x3FFu & inv_k) | (~0x3FFu & u);
    return __builtin_bit_cast(float, r);
}

// ---- Prep: normalize centers -> fp8 chat, store fp32 norms; zero d_out ----
__global__ void prep_centers(const float* __restrict__ centers,
                             unsigned char* __restrict__ chat,
                             float* __restrict__ cnorm,
                             float* __restrict__ out) {
    const int k = blockIdx.x;
    const int t = threadIdx.x;            // 128 threads, one per dim
    float v = centers[(size_t)k * D + t];
    float s = v * v;
    #pragma unroll
    for (int m = 1; m <= 32; m <<= 1) s += __shfl_xor(s, m);
    __shared__ float ws2[2];
    if ((t & 63) == 0) ws2[t >> 6] = s;
    __syncthreads();
    float total = ws2[0] + ws2[1];
    float n = sqrtf(total);
    float neff = fmaxf(n, 1e-12f);
    float q = v / neff;
    chat[(size_t)k * D + t] = (unsigned char)(pk_fp8<false>(q, q, 0u) & 0xFFu);
    if (t == 0) cnorm[k] = n;
    if (k == 0 && t == 0) out[0] = 0.0f;
}

// ---- Main ----
__global__ __launch_bounds__(1024, 4) void cluster_main(
    const float* __restrict__ feats,        // [N][128] fp32
    const unsigned char* __restrict__ chat, // [1024][128] fp8 e4m3
    const float* __restrict__ cnorm,        // [1024] fp32
    float* __restrict__ out, int N, int rtPer) {

    extern __shared__ unsigned char lds[];
    unsigned char* Bs = lds;                 // 131072 B, swizzled
    unsigned char* As = lds + NK * D;        // 16384 B, swizzled
    __shared__ float nf_s[128];
    __shared__ float bv[8][128];             // keyed floats per (wn,row)

    const int tid  = threadIdx.x;            // 0..1023, 16 waves
    const int lane = tid & 63;
    const int wave = tid >> 6;
    const int wm   = wave & 1;               // row half (64 rows)
    const int wn   = wave >> 1;              // col slice (128 centers)
    const int m16  = lane & 15;
    const int quad = lane >> 4;              // 0..3
    const int q1   = quad >> 1, q0 = quad & 1;
    const int m8   = m16 & 7;

    // ---- Stage ALL of B once: 8192 16B chunks, 8/thread, swizzled ----
    #pragma unroll
    for (int s = 0; s < 8; ++s) {
        int id = s * 1024 + tid;
        int r  = id >> 3;                    // center row
        int c  = id & 7;                     // logical 16B chunk
        uint4 v = *(const uint4*)(chat + (size_t)r * D + c * 16);
        *(uint4*)&Bs[r * D + ((c ^ (r & 7)) << 4)] = v;
    }

    for (int rt = 0; rt < rtPer; ++rt) {
        const int row0 = (blockIdx.x * rtPer + rt) * 128;

        // ---- Stage A (coalesced float4 -> fp8, swizzled) + row sumsq ----
        #pragma unroll
        for (int s = 0; s < 4; ++s) {
            int id = s * 1024 + tid;         // float4 chunk, 0..4095
            int r  = id >> 5;                // row (32 chunks/row)
            int c4 = id & 31;
            float4 v = *(const float4*)(feats + (size_t)(row0 + r) * D + c4 * 4);
            unsigned int w = pk_fp8<false>(v.x, v.y, 0u);
            w = pk_fp8<true>(v.z, v.w, w);
            int pc = (c4 >> 2) ^ (r & 7);    // swizzled 16B chunk
            *(unsigned int*)&As[r * D + pc * 16 + (c4 & 3) * 4] = w;
            float sq = v.x*v.x + v.y*v.y + v.z*v.z + v.w*v.w;
            #pragma unroll
            for (int m = 1; m <= 16; m <<= 1) sq += __shfl_xor(sq, m);
            if ((tid & 31) == 0) nf_s[r] = sq;
        }
        __syncthreads();                     // B (rt 0) + A + nf_s visible

        // ---- A fragments from LDS (2-way banks, free) ----
        long long afr[4][4];                 // [i][kk]
        #pragma unroll
        for (int i = 0; i < 4; ++i) {
            const int r = wm * 64 + i * 16 + m16;
            #pragma unroll
            for (int kk = 0; kk < 4; ++kk) {
                int pc = (2 * kk + q1) ^ m8;
                afr[i][kk] = *(const long long*)&As[r * D + pc * 16 + q0 * 8];
            }
        }

        float best[16];                      // keyed floats, per (i,r) slot
        #pragma unroll
        for (int s = 0; s < 16; ++s) best[s] = -3.0e38f;

        // ---- barrier-free MFMA over this wave's 128-center slice ----
        #pragma unroll
        for (int ch = 0; ch < 4; ++ch) {     // 4 chunks of 32 centers
            const int cbase = wn * 128 + ch * 32;
            const unsigned int inv0 = 1023u - (unsigned)(cbase + m16);       // j=0
            const unsigned int inv1 = inv0 - 16u;                            // j=1
            floatx4 acc[4][2];
            #pragma unroll
            for (int i = 0; i < 4; ++i)
                #pragma unroll
                for (int j = 0; j < 2; ++j)
                    acc[i][j] = (floatx4){0.f, 0.f, 0.f, 0.f};

            #pragma unroll
            for (int kk = 0; kk < 4; ++kk) {
                long long bfr[2];
                #pragma unroll
                for (int j = 0; j < 2; ++j) {
                    int k  = cbase + j * 16 + m16;
                    int pc = (2 * kk + q1) ^ m8;
                    bfr[j] = *(const long long*)&Bs[k * D + pc * 16 + q0 * 8];
                }
                #pragma unroll
                for (int i = 0; i < 4; ++i)
                    #pragma unroll
                    for (int j = 0; j < 2; ++j)
                        acc[i][j] = __builtin_amdgcn_mfma_f32_16x16x32_fp8_fp8(
                            afr[i][kk], bfr[j], acc[i][j], 0, 0, 0);
            }

            // keyed argmax: bfi + max3 per pair of candidates
            #pragma unroll
            for (int i = 0; i < 4; ++i)
                #pragma unroll
                for (int r = 0; r < 4; ++r) {
                    const int slot = i * 4 + r;
                    float c0 = key_pack(acc[i][0][r], inv0);
                    float c1 = key_pack(acc[i][1][r], inv1);
                    best[slot] = fmaxf(best[slot], fmaxf(c0, c1));
                }
        }

        // cross-m16 butterfly (same rows, different cols) — pure max on keys
        #pragma unroll
        for (int mask = 1; mask <= 8; mask <<= 1)
            #pragma unroll
            for (int s = 0; s < 16; ++s)
                best[s] = fmaxf(best[s], __shfl_xor(best[s], mask));

        if (m16 == 0) {
            #pragma unroll
            for (int s = 0; s < 16; ++s) {
                int i = s >> 2, rr = s & 3;
                int row = wm * 64 + 16 * i + quad * 4 + rr;
                bv[wn][row] = best[s];
            }
        }
        __syncthreads();

        // ---- combine 8 col-slices; decode; loss; reduce ----
        if (tid < 128) {
            const int row = tid;
            float kmax = bv[0][row];
            #pragma unroll
            for (int w = 1; w < 8; ++w) kmax = fmaxf(kmax, bv[w][row]);
            unsigned int ub = __builtin_bit_cast(unsigned int, kmax);
            int   ka = 1023 - (int)(ub & 1023u);
            float d  = __builtin_bit_cast(float, (ub & 0xFFFFFC00u) | 0x200u);
            float nf = fmaxf(sqrtf(nf_s[row]), 1e-12f);
            float na = cnorm[ka];
            float lsum = 1.0f - 2.0f * d * na / nf + na * na;
            #pragma unroll
            for (int m = 1; m <= 32; m <<= 1) lsum += __shfl_xor(lsum, m);
            if (lane == 0) atomicAdd(out, lsum / (float)N);
        }
        __syncthreads();   // protect As/nf_s/bv before next rt
    }
}

extern "C" void kernel_launch(void* const* d_in, const int* in_sizes, int n_in,
                              void* d_out, int out_size, void* d_ws, size_t ws_size,
                              hipStream_t stream) {
    const float* feats   = (const float*)d_in[0];
    const float* centers = (const float*)d_in[1];
    const int N = in_sizes[0] / D;   // 131072
    const int K = in_sizes[1] / D;   // 1024

    unsigned char* chat = (unsigned char*)d_ws;                    // 1024*128 fp8 = 128 KB
    float* cnorm = (float*)((char*)d_ws + (size_t)K * D);          // K fp32
    float* out = (float*)d_out;

    const int smem = NK * D + 128 * D;   // 147456 B dynamic
    (void)hipFuncSetAttribute((const void*)cluster_main,
                              hipFuncAttributeMaxDynamicSharedMemorySize, smem);

    prep_centers<<<K, D, 0, stream>>>(centers, chat, cnorm, out);

    const int nTiles = N / 128;              // 1024
    const int grid = 256;
    const int rtPer = nTiles / grid;         // 4
    cluster_main<<<grid, 1024, smem, stream>>>(feats, chat, cnorm, out, N, rtPer);
}

// Round 7
// 139.277 us; speedup vs baseline: 1.2853x; 1.1129x over previous
//
#include <hip/hip_runtime.h>
#include <hip/hip_bf16.h>

// ClusterLoss fused kernel for MI355X (gfx950).  R7.
// = R6 structure (whole-B-in-LDS fp8 XOR-swizzled, coalesced A staging via
// 16 KB swizzled LDS tile, keyed-float argmax) but 512 threads/block:
// R5/R6's 1024-thread blocks pinned the allocator at 64 VGPR -> 18 MB scratch
// spill traffic in the hot loop. R4 proved 512-thread blocks get ~112 VGPR
// with zero spill. 8 waves (2/SIMD); each wave covers 256 centers.
// loss_n = 1 - 2 d na/nf + na^2 (fp32 scalars).

#define D 128
#define NK 1024

typedef __attribute__((ext_vector_type(4))) float floatx4;

template <bool HI>
__device__ __forceinline__ unsigned int pk_fp8(float a, float b, unsigned int old) {
    return (unsigned int)__builtin_amdgcn_cvt_pk_fp8_f32(a, b, (int)old, HI);
}

__device__ __forceinline__ float key_pack(float v, unsigned int inv_k) {
    unsigned int u = __builtin_bit_cast(unsigned int, v);
    unsigned int r = (0x3FFu & inv_k) | (~0x3FFu & u);   // v_bfi_b32
    return __builtin_bit_cast(float, r);
}

// ---- Prep: normalize centers -> fp8 chat, store fp32 norms; zero d_out ----
__global__ void prep_centers(const float* __restrict__ centers,
                             unsigned char* __restrict__ chat,
                             float* __restrict__ cnorm,
                             float* __restrict__ out) {
    const int k = blockIdx.x;
    const int t = threadIdx.x;            // 128 threads, one per dim
    float v = centers[(size_t)k * D + t];
    float s = v * v;
    #pragma unroll
    for (int m = 1; m <= 32; m <<= 1) s += __shfl_xor(s, m);
    __shared__ float ws2[2];
    if ((t & 63) == 0) ws2[t >> 6] = s;
    __syncthreads();
    float total = ws2[0] + ws2[1];
    float n = sqrtf(total);
    float neff = fmaxf(n, 1e-12f);
    float q = v / neff;
    chat[(size_t)k * D + t] = (unsigned char)(pk_fp8<false>(q, q, 0u) & 0xFFu);
    if (t == 0) cnorm[k] = n;
    if (k == 0 && t == 0) out[0] = 0.0f;
}

// ---- Main ----
__global__ __launch_bounds__(512, 1) void cluster_main(
    const float* __restrict__ feats,        // [N][128] fp32
    const unsigned char* __restrict__ chat, // [1024][128] fp8 e4m3
    const float* __restrict__ cnorm,        // [1024] fp32
    float* __restrict__ out, int N, int rtPer) {

    extern __shared__ unsigned char lds[];
    unsigned char* Bs = lds;                 // 131072 B, swizzled
    unsigned char* As = lds + NK * D;        // 16384 B, swizzled
    __shared__ float nf_s[128];
    __shared__ float bv[4][128];             // keyed floats per (wn,row)

    const int tid  = threadIdx.x;            // 0..511, 8 waves
    const int lane = tid & 63;
    const int wave = tid >> 6;
    const int wm   = wave & 1;               // row half (64 rows)
    const int wn   = wave >> 1;              // col slice (256 centers)
    const int m16  = lane & 15;
    const int quad = lane >> 4;              // 0..3
    const int q1   = quad >> 1, q0 = quad & 1;
    const int m8   = m16 & 7;

    // ---- Stage ALL of B once: 8192 16B chunks, 16/thread, swizzled ----
    #pragma unroll
    for (int s = 0; s < 16; ++s) {
        int id = s * 512 + tid;
        int r  = id >> 3;                    // center row
        int c  = id & 7;                     // logical 16B chunk
        uint4 v = *(const uint4*)(chat + (size_t)r * D + c * 16);
        *(uint4*)&Bs[r * D + ((c ^ (r & 7)) << 4)] = v;
    }

    for (int rt = 0; rt < rtPer; ++rt) {
        const int row0 = (blockIdx.x * rtPer + rt) * 128;

        // ---- Stage A (coalesced float4 -> fp8, swizzled) + row sumsq ----
        #pragma unroll
        for (int s = 0; s < 8; ++s) {
            int id = s * 512 + tid;          // float4 chunk, 0..4095
            int r  = id >> 5;                // row (32 chunks/row)
            int c4 = id & 31;
            float4 v = *(const float4*)(feats + (size_t)(row0 + r) * D + c4 * 4);
            unsigned int w = pk_fp8<false>(v.x, v.y, 0u);
            w = pk_fp8<true>(v.z, v.w, w);
            int pc = (c4 >> 2) ^ (r & 7);    // swizzled 16B chunk
            *(unsigned int*)&As[r * D + pc * 16 + (c4 & 3) * 4] = w;
            float sq = v.x*v.x + v.y*v.y + v.z*v.z + v.w*v.w;
            #pragma unroll
            for (int m = 1; m <= 16; m <<= 1) sq += __shfl_xor(sq, m);
            if ((tid & 31) == 0) nf_s[r] = sq;
        }
        __syncthreads();                     // B (rt 0) + A + nf_s visible

        // ---- A fragments from LDS (2-way banks, free) ----
        long long afr[4][4];                 // [i][kk]
        #pragma unroll
        for (int i = 0; i < 4; ++i) {
            const int r = wm * 64 + i * 16 + m16;
            #pragma unroll
            for (int kk = 0; kk < 4; ++kk) {
                int pc = (2 * kk + q1) ^ m8;
                afr[i][kk] = *(const long long*)&As[r * D + pc * 16 + q0 * 8];
            }
        }

        float best[16];                      // keyed floats, per (i,r) slot
        #pragma unroll
        for (int s = 0; s < 16; ++s) best[s] = -3.0e38f;

        // ---- barrier-free MFMA over this wave's 256-center slice ----
        #pragma unroll
        for (int ch = 0; ch < 8; ++ch) {     // 8 chunks of 32 centers
            const int cbase = wn * 256 + ch * 32;
            const unsigned int inv0 = 1023u - (unsigned)(cbase + m16);   // j=0
            const unsigned int inv1 = inv0 - 16u;                        // j=1
            floatx4 acc[4][2];
            #pragma unroll
            for (int i = 0; i < 4; ++i)
                #pragma unroll
                for (int j = 0; j < 2; ++j)
                    acc[i][j] = (floatx4){0.f, 0.f, 0.f, 0.f};

            #pragma unroll
            for (int kk = 0; kk < 4; ++kk) {
                long long bfr[2];
                #pragma unroll
                for (int j = 0; j < 2; ++j) {
                    int k  = cbase + j * 16 + m16;
                    int pc = (2 * kk + q1) ^ m8;
                    bfr[j] = *(const long long*)&Bs[k * D + pc * 16 + q0 * 8];
                }
                #pragma unroll
                for (int i = 0; i < 4; ++i)
                    #pragma unroll
                    for (int j = 0; j < 2; ++j)
                        acc[i][j] = __builtin_amdgcn_mfma_f32_16x16x32_fp8_fp8(
                            afr[i][kk], bfr[j], acc[i][j], 0, 0, 0);
            }

            // keyed argmax: bfi + max per candidate pair
            #pragma unroll
            for (int i = 0; i < 4; ++i)
                #pragma unroll
                for (int r = 0; r < 4; ++r) {
                    const int slot = i * 4 + r;
                    float c0 = key_pack(acc[i][0][r], inv0);
                    float c1 = key_pack(acc[i][1][r], inv1);
                    best[slot] = fmaxf(best[slot], fmaxf(c0, c1));
                }
        }

        // cross-m16 butterfly (same rows, different cols) — pure max on keys
        #pragma unroll
        for (int mask = 1; mask <= 8; mask <<= 1)
            #pragma unroll
            for (int s = 0; s < 16; ++s)
                best[s] = fmaxf(best[s], __shfl_xor(best[s], mask));

        if (m16 == 0) {
            #pragma unroll
            for (int s = 0; s < 16; ++s) {
                int i = s >> 2, rr = s & 3;
                int row = wm * 64 + 16 * i + quad * 4 + rr;
                bv[wn][row] = best[s];
            }
        }
        __syncthreads();

        // ---- combine 4 col-slices; decode; loss; reduce ----
        if (tid < 128) {
            const int row = tid;
            float kmax = fmaxf(fmaxf(bv[0][row], bv[1][row]),
                               fmaxf(bv[2][row], bv[3][row]));
            unsigned int ub = __builtin_bit_cast(unsigned int, kmax);
            int   ka = 1023 - (int)(ub & 1023u);
            float d  = __builtin_bit_cast(float, (ub & 0xFFFFFC00u) | 0x200u);
            float nf = fmaxf(sqrtf(nf_s[row]), 1e-12f);
            float na = cnorm[ka];
            float lsum = 1.0f - 2.0f * d * na / nf + na * na;
            #pragma unroll
            for (int m = 1; m <= 32; m <<= 1) lsum += __shfl_xor(lsum, m);
            if (lane == 0) atomicAdd(out, lsum / (float)N);
        }
        __syncthreads();   // protect As/nf_s/bv before next rt
    }
}

extern "C" void kernel_launch(void* const* d_in, const int* in_sizes, int n_in,
                              void* d_out, int out_size, void* d_ws, size_t ws_size,
                              hipStream_t stream) {
    const float* feats   = (const float*)d_in[0];
    const float* centers = (const float*)d_in[1];
    const int N = in_sizes[0] / D;   // 131072
    const int K = in_sizes[1] / D;   // 1024

    unsigned char* chat = (unsigned char*)d_ws;                    // 1024*128 fp8 = 128 KB
    float* cnorm = (float*)((char*)d_ws + (size_t)K * D);          // K fp32
    float* out = (float*)d_out;

    const int smem = NK * D + 128 * D;   // 147456 B dynamic
    (void)hipFuncSetAttribute((const void*)cluster_main,
                              hipFuncAttributeMaxDynamicSharedMemorySize, smem);

    prep_centers<<<K, D, 0, stream>>>(centers, chat, cnorm, out);

    const int nTiles = N / 128;              // 1024
    const int grid = 256;
    const int rtPer = nTiles / grid;         // 4
    cluster_main<<<grid, 512, smem, stream>>>(feats, chat, cnorm, out, N, rtPer);
}